// Round 6
// baseline (27.864 us; speedup 1.0000x reference)
//
#include <hip/hip_runtime.h>

#define N_SAMPLES 128
#define NUM_OBJECTS 8
#define NUM_POINTS 100000
#define GROUPS 25000           // groups of 4 points (48 B / 12 floats each)
#define TPB 256
#define CHUNKS 64              // 64 blocks/object * 256 thr * 2 groups = 32768 >= 25000
#define MAXS 128

// 4 packed points from 12 floats f[0..11]:
// p0=(f0,f1,f2) p1=(f3,f4,f5) p2=(f6,f7,f8) p3=(f9,f10,f11)
__device__ __forceinline__ float pts4_l1(
    const float* __restrict__ f,
    float d0, float d1, float d2, float d3, float d4,
    float d5, float d6, float d7, float d8)
{
    float s;
    s  = fabsf(d0 * f[0] + d1 * f[1]  + d2 * f[2])
       + fabsf(d3 * f[0] + d4 * f[1]  + d5 * f[2])
       + fabsf(d6 * f[0] + d7 * f[1]  + d8 * f[2]);
    s += fabsf(d0 * f[3] + d1 * f[4]  + d2 * f[5])
       + fabsf(d3 * f[3] + d4 * f[4]  + d5 * f[5])
       + fabsf(d6 * f[3] + d7 * f[4]  + d8 * f[5]);
    s += fabsf(d0 * f[6] + d1 * f[7]  + d2 * f[8])
       + fabsf(d3 * f[6] + d4 * f[7]  + d5 * f[8])
       + fabsf(d6 * f[6] + d7 * f[7]  + d8 * f[8]);
    s += fabsf(d0 * f[9] + d1 * f[10] + d2 * f[11])
       + fabsf(d3 * f[9] + d4 * f[10] + d5 * f[11])
       + fabsf(d6 * f[9] + d7 * f[10] + d8 * f[11]);
    return s;
}

// Single fused kernel. grid = (CHUNKS, NUM_OBJECTS), 512 blocks = 2/CU.
// Each thread holds 8 points in registers; per-sample 5-level within-32
// shuffle reduce -> 8 half-wave partials in LDS -> one post-loop atomicAdd
// per (sample, block) into pre-zeroed out[0..128). Block (0,0) also writes
// the two translation losses with plain stores.
__global__ __launch_bounds__(TPB) void pm_fused_kernel(
    const int* __restrict__ obj_id,
    const float* __restrict__ gtR, const float* __restrict__ prR,
    const float* __restrict__ gt_t, const float* __restrict__ pred_t,
    const float* __restrict__ pts, const float* __restrict__ diam,
    float* __restrict__ out)
{
    const int o     = blockIdx.y;
    const int chunk = blockIdx.x;
    const int tid   = threadIdx.x;

    __shared__ int   s_cnt;
    __shared__ int   s_sidx[MAXS];
    __shared__ float s_dR[MAXS][12];      // rows padded to 12 for b128 reads
    __shared__ float s_part[8][MAXS];     // 8 half-wave partials per sample

    if (tid == 0) s_cnt = 0;
    // fold the trivial translation losses into block (0,0)'s upper half
    if (chunk == 0 && o == 0 && tid >= 128) {
        const int n = tid - 128;
        out[N_SAMPLES + n] = fabsf(gt_t[n * 3 + 0] - pred_t[n * 3 + 0])
                           + fabsf(gt_t[n * 3 + 1] - pred_t[n * 3 + 1]);
        out[2 * N_SAMPLES + n] = fabsf(gt_t[n * 3 + 2] - pred_t[n * 3 + 2]);
    }
    __syncthreads();
    if (tid < N_SAMPLES) {
        const int n = tid;
        if (obj_id[n] == o) {
            int slot = atomicAdd(&s_cnt, 1);   // LDS atomic, one-time
            s_sidx[slot] = n;
            #pragma unroll
            for (int j = 0; j < 9; ++j)
                s_dR[slot][j] = prR[n * 9 + j] - gtR[n * 9 + j];
        }
    }
    __syncthreads();
    const int nsamp = s_cnt;
    if (nsamp == 0) return;               // object unused: nothing owed
    const int nsamp_pad = (nsamp + 3) & ~3;
    {   // zero the <=3 pad rows
        const int idx = nsamp + tid;
        if (idx < nsamp_pad) {
            #pragma unroll
            for (int j = 0; j < 9; ++j) s_dR[idx][j] = 0.0f;
        }
    }
    __syncthreads();

    const float fscale = 1.0f / ((float)NUM_POINTS * diam[o]);

    // Load this thread's 8 points (two groups of 4) once.
    const float4* __restrict__ p4 =
        (const float4*)(pts + (size_t)o * (size_t)NUM_POINTS * 3);
    const int g0 = chunk * TPB + tid;     // <= 16383 < GROUPS: always valid
    const int g1 = g0 + CHUNKS * TPB;     // may exceed GROUPS
    float4 a0 = p4[g0 * 3 + 0], b0 = p4[g0 * 3 + 1], c0 = p4[g0 * 3 + 2];
    const float valid = (g1 < GROUPS) ? 1.0f : 0.0f;
    const int g1c = min(g1, GROUPS - 1);
    float4 a1 = p4[g1c * 3 + 0], b1 = p4[g1c * 3 + 1], c1 = p4[g1c * 3 + 2];
    float f0[12] = { a0.x, a0.y, a0.z, a0.w, b0.x, b0.y,
                     b0.z, b0.w, c0.x, c0.y, c0.z, c0.w };
    float f1[12] = { a1.x * valid, a1.y * valid, a1.z * valid, a1.w * valid,
                     b1.x * valid, b1.y * valid, b1.z * valid, b1.w * valid,
                     c1.x * valid, c1.y * valid, c1.z * valid, c1.w * valid };

    const int lane = tid & 63;
    const int half = (tid >> 6) * 2 + ((lane >> 5) & 1);

    for (int s0 = 0; s0 < nsamp_pad; s0 += 4) {
        float acc[4];
        #pragma unroll
        for (int k = 0; k < 4; ++k) {
            float4 q0 = *(const float4*)&s_dR[s0 + k][0];
            float4 q1 = *(const float4*)&s_dR[s0 + k][4];
            float4 q2 = *(const float4*)&s_dR[s0 + k][8];
            acc[k] = pts4_l1(f0, q0.x, q0.y, q0.z, q0.w,
                                 q1.x, q1.y, q1.z, q1.w, q2.x)
                   + pts4_l1(f1, q0.x, q0.y, q0.z, q0.w,
                                 q1.x, q1.y, q1.z, q1.w, q2.x);
        }
        #pragma unroll
        for (int off = 1; off <= 16; off <<= 1) {
            #pragma unroll
            for (int k = 0; k < 4; ++k)
                acc[k] += __shfl_xor(acc[k], off, 64);
        }
        if ((lane & 31) == 0) {
            #pragma unroll
            for (int k = 0; k < 4; ++k)
                s_part[half][s0 + k] = acc[k];
        }
    }
    __syncthreads();

    // One atomic per (sample, block), post-loop; out[0..128) pre-zeroed by
    // the hipMemsetAsync in kernel_launch.
    if (tid < nsamp) {
        float v = 0.0f;
        #pragma unroll
        for (int w = 0; w < 8; ++w) v += s_part[w][tid];
        atomicAdd(&out[s_sidx[tid]], v * fscale);
    }
}

extern "C" void kernel_launch(void* const* d_in, const int* in_sizes, int n_in,
                              void* d_out, int out_size, void* d_ws, size_t ws_size,
                              hipStream_t stream) {
    const int*   obj_id = (const int*)d_in[0];
    const float* gtR    = (const float*)d_in[1];
    const float* prR    = (const float*)d_in[2];
    const float* gt_t   = (const float*)d_in[3];
    const float* pred_t = (const float*)d_in[4];
    const float* pts    = (const float*)d_in[5];
    const float* diam   = (const float*)d_in[6];
    float* out = (float*)d_out;

    // zero only the 128 pm accumulators (tiny fill, graph-capturable)
    hipMemsetAsync(out, 0, N_SAMPLES * sizeof(float), stream);
    pm_fused_kernel<<<dim3(CHUNKS, NUM_OBJECTS), TPB, 0, stream>>>(
        obj_id, gtR, prR, gt_t, pred_t, pts, diam, out);
}

// Round 7
// 21.147 us; speedup vs baseline: 1.3177x; 1.3177x over previous
//
#include <hip/hip_runtime.h>

#define N_SAMPLES 128
#define NUM_OBJECTS 8
#define NUM_POINTS 100000
#define GROUPS 25000           // float4-groups of 4 points (48 B each)
#define TPB 1024
#define ITERS 25               // ceil(25000/1024); last iter partial (tid<424)

// Single kernel, single dispatch. One block per sample; block b handles the
// r-th sample in object-grouped order with r=(b&7)*16+(b>>3), so blocks that
// land on the same XCD (round-robin blockIdx%8) share one object's 1.2 MB
// point set in that XCD's L2. All reductions are intra-block; every out
// element is written exactly once by a plain store (no atomics, no memset,
// no workspace, poison-proof).
__global__ __launch_bounds__(TPB) void pm_onepass_kernel(
    const int* __restrict__ obj_id,
    const float* __restrict__ gtR, const float* __restrict__ prR,
    const float* __restrict__ gt_t, const float* __restrict__ pred_t,
    const float* __restrict__ pts, const float* __restrict__ diam,
    float* __restrict__ out)
{
    const int b   = blockIdx.x;
    const int tid = threadIdx.x;

    __shared__ int   s_oid[N_SAMPLES];
    __shared__ int   s_r2s[N_SAMPLES];   // grouped rank -> sample index
    __shared__ float s_wsum[TPB / 64];

    if (tid < N_SAMPLES) s_oid[tid] = obj_id[tid];
    __syncthreads();
    if (tid < N_SAMPLES) {
        // global grouped rank of sample tid: #(m : oid[m]<o) + #(m<tid : oid[m]==o)
        const int o = s_oid[tid];
        int rank = 0;
        for (int m = 0; m < N_SAMPLES; ++m) {   // LDS broadcast reads
            const int om = s_oid[m];
            rank += (om < o) || (om == o && m < tid);
        }
        s_r2s[rank] = tid;
    }
    __syncthreads();

    const int r = (b & 7) * 16 + (b >> 3);               // block-uniform
    const int n = __builtin_amdgcn_readfirstlane(s_r2s[r]);
    const int o = __builtin_amdgcn_readfirstlane(s_oid[n]);

    // dR in scalar regs (uniform address -> s_load)
    float d0 = prR[n * 9 + 0] - gtR[n * 9 + 0];
    float d1 = prR[n * 9 + 1] - gtR[n * 9 + 1];
    float d2 = prR[n * 9 + 2] - gtR[n * 9 + 2];
    float d3 = prR[n * 9 + 3] - gtR[n * 9 + 3];
    float d4 = prR[n * 9 + 4] - gtR[n * 9 + 4];
    float d5 = prR[n * 9 + 5] - gtR[n * 9 + 5];
    float d6 = prR[n * 9 + 6] - gtR[n * 9 + 6];
    float d7 = prR[n * 9 + 7] - gtR[n * 9 + 7];
    float d8 = prR[n * 9 + 8] - gtR[n * 9 + 8];

    const float4* __restrict__ p4 =
        (const float4*)(pts + (size_t)o * (size_t)NUM_POINTS * 3);

    float acc = 0.0f;
    #pragma unroll 2
    for (int i = 0; i < ITERS; ++i) {
        const int g = i * TPB + tid;
        if (g < GROUPS) {
            float4 a = p4[g * 3 + 0];
            float4 c = p4[g * 3 + 1];
            float4 e = p4[g * 3 + 2];
            // p0=(a.x,a.y,a.z) p1=(a.w,c.x,c.y) p2=(c.z,c.w,e.x) p3=(e.y,e.z,e.w)
            acc += fabsf(d0 * a.x + d1 * a.y + d2 * a.z)
                 + fabsf(d3 * a.x + d4 * a.y + d5 * a.z)
                 + fabsf(d6 * a.x + d7 * a.y + d8 * a.z);
            acc += fabsf(d0 * a.w + d1 * c.x + d2 * c.y)
                 + fabsf(d3 * a.w + d4 * c.x + d5 * c.y)
                 + fabsf(d6 * a.w + d7 * c.x + d8 * c.y);
            acc += fabsf(d0 * c.z + d1 * c.w + d2 * e.x)
                 + fabsf(d3 * c.z + d4 * c.w + d5 * e.x)
                 + fabsf(d6 * c.z + d7 * c.w + d8 * e.x);
            acc += fabsf(d0 * e.y + d1 * e.z + d2 * e.w)
                 + fabsf(d3 * e.y + d4 * e.z + d5 * e.w)
                 + fabsf(d6 * e.y + d7 * e.z + d8 * e.w);
        }
    }

    // full-wave reduce (6 levels), then LDS across the 16 waves
    #pragma unroll
    for (int off = 1; off <= 32; off <<= 1)
        acc += __shfl_xor(acc, off, 64);
    if ((tid & 63) == 0) s_wsum[tid >> 6] = acc;
    __syncthreads();

    if (tid < 3) {
        if (tid == 0) {
            float v = 0.0f;
            #pragma unroll
            for (int w = 0; w < TPB / 64; ++w) v += s_wsum[w];
            out[n] = v / ((float)NUM_POINTS * diam[o]);
        } else if (tid == 1) {
            out[N_SAMPLES + n] = fabsf(gt_t[n * 3 + 0] - pred_t[n * 3 + 0])
                               + fabsf(gt_t[n * 3 + 1] - pred_t[n * 3 + 1]);
        } else {
            out[2 * N_SAMPLES + n] = fabsf(gt_t[n * 3 + 2] - pred_t[n * 3 + 2]);
        }
    }
}

extern "C" void kernel_launch(void* const* d_in, const int* in_sizes, int n_in,
                              void* d_out, int out_size, void* d_ws, size_t ws_size,
                              hipStream_t stream) {
    const int*   obj_id = (const int*)d_in[0];
    const float* gtR    = (const float*)d_in[1];
    const float* prR    = (const float*)d_in[2];
    const float* gt_t   = (const float*)d_in[3];
    const float* pred_t = (const float*)d_in[4];
    const float* pts    = (const float*)d_in[5];
    const float* diam   = (const float*)d_in[6];
    float* out = (float*)d_out;

    pm_onepass_kernel<<<N_SAMPLES, TPB, 0, stream>>>(
        obj_id, gtR, prR, gt_t, pred_t, pts, diam, out);
}